// Round 7
// baseline (138.189 us; speedup 1.0000x reference)
//
#include <hip/hip_runtime.h>
#include <hip/hip_fp16.h>

// HierarchicalStaticNeuralTexture — round 7: consolidated pipeline.
//
//   uv_inputs: [1, 2, 1024, 1024] f32, coords in [-1,1]
//   data:      [1, 16, 2048, 1024] f32  (4 mip levels stacked in Y)
//   out:       [1, 16, 1024, 1024] f32 = sum over 4 levels of bilinear
//              grid_sample (border padding, align_corners=False)
//
// Pipeline (6 kernels):
//   K1 prep     : [blocks 0..1023] per-block UV histogram (float4 loads)
//                 [blocks 1024..6463] atlas -> fp16 texel-major transpose
//   K2 scan_a   : chunk-local exclusive scan of cnt (32 WGs)
//   K3 scan_b   : bucket bases + chunk offsets (1 WG)
//   K4 scatter2 : LDS ranks -> uvs[pos], inv[idx] (float4 loads)
//   K5 sample_b : sorted-order sampling (bucket-local L2 reuse) -> fp16 tmp
//   K6 unperm   : 4 px/thread gather of tmp, float4 plane stores

#define IMG 1024
#define NPIX (IMG * IMG)
#define NCH 16
#define DATA_ROWSTRIDE 1024
#define DATA_CHSTRIDE (2048 * 1024)
#define NBUCK 1024
#define NBLK 1024            // sort blocks, 1024 px each
#define NW 32                // chunks of 32 blocks

// Compact texel-major layout (texel index -> 16 halves)
#define L0_BASE 0
#define L1_BASE 1048576
#define L2_BASE 1310720
#define L3_BASE 1376256
#define TOT_TEXELS 1392640
#define TRANS_BLKS (TOT_TEXELS / 256)   // 5440

// Workspace layout (bytes). cnt/wgsum/wgoff alias the head of tmp
// (dead before sample_b writes tmp).
#define TEX_BYTES  44564480ull
#define UVS_OFF    44564480ull                    // float2 * NPIX = 8 MB
#define INV_OFF    52953088ull                    // u32 * NPIX   = 4 MB
#define TMP_OFF    57147392ull                    // half*16*NPIX = 32 MB
#define CNT_OFF    TMP_OFF                        // u32[1024][1024] = 4 MB
#define WGS_OFF    (CNT_OFF + 4194304ull)         // u32[32][1024] = 128 KB
#define WGO_OFF    (WGS_OFF + 131072ull)          // u32[32][1024] = 128 KB
#define WS_FULL    90701824ull                    // proven available (r5/r6)
#define WS_DIRECT  TEX_BYTES

// ---------------- bucket key: 32x32 tiles of the L0 texel grid ---------------
__device__ __forceinline__ int bucket_of(const float gx, const float gy)
{
    const float x = fminf(fmaxf(fmaf(gx + 1.0f, 512.0f, -0.5f), 0.0f), 1023.0f);
    const float y = fminf(fmaxf(fmaf(gy + 1.0f, 512.0f, -0.5f), 0.0f), 1023.0f);
    return (((int)y) >> 5) * 32 + (((int)x) >> 5);
}

// ---------------- K1: histogram (blocks 0..1023) ∥ transpose (rest) ----------
__global__ __launch_bounds__(256) void hsnt_prep(
    const float* __restrict__ data, const float* __restrict__ uv,
    __half* __restrict__ tex, unsigned* __restrict__ cnt)
{
    __shared__ unsigned lh[NBUCK];

    if (blockIdx.x < NBLK) {
        // ---- histogram over 1024 px, float4 loads, 4 px / thread ----
        const int blk = blockIdx.x;
        for (int i = threadIdx.x; i < NBUCK; i += 256) lh[i] = 0u;
        __syncthreads();

        const int i4 = blk * 1024 + threadIdx.x * 4;
        const float4 gx4 = *(const float4*)&uv[i4];
        const float4 gy4 = *(const float4*)&uv[NPIX + i4];
        atomicAdd(&lh[bucket_of(gx4.x, gy4.x)], 1u);
        atomicAdd(&lh[bucket_of(gx4.y, gy4.y)], 1u);
        atomicAdd(&lh[bucket_of(gx4.z, gy4.z)], 1u);
        atomicAdd(&lh[bucket_of(gx4.w, gy4.w)], 1u);
        __syncthreads();

        unsigned* row = cnt + (size_t)blk * NBUCK;
        for (int i = threadIdx.x; i < NBUCK; i += 256) row[i] = lh[i];
    } else {
        // ---- transpose+quantize one 256-texel slab ----
        int b = blockIdx.x - NBLK;
        int base, offY, logW;
        if (b < 4096)      { base = L0_BASE; offY = 0;    logW = 10; }
        else if (b < 5120) { base = L1_BASE; offY = 1024; logW = 9;  b -= 4096; }
        else if (b < 5376) { base = L2_BASE; offY = 1536; logW = 8;  b -= 5120; }
        else               { base = L3_BASE; offY = 1792; logW = 7;  b -= 5376; }

        const int t = b * 256 + threadIdx.x;
        const int y = t >> logW;
        const int x = t & ((1 << logW) - 1);

        const float* src = data + (size_t)(offY + y) * DATA_ROWSTRIDE + x;
        __half h[NCH];
#pragma unroll
        for (int c = 0; c < NCH; ++c)
            h[c] = __float2half(src[(size_t)c * DATA_CHSTRIDE]);

        uint4* dst = (uint4*)(tex + ((size_t)(base + t) << 4));
        dst[0] = *(const uint4*)&h[0];
        dst[1] = *(const uint4*)&h[8];
    }
}

// ---------------- K2: chunk-level exclusive scan (in place) ------------------
__global__ __launch_bounds__(1024) void hsnt_scan_a(
    unsigned* __restrict__ cnt, unsigned* __restrict__ wgsum)
{
    const int w = blockIdx.x;
    const int b = threadIdx.x;
    unsigned sum = 0u;
#pragma unroll 4
    for (int r = 0; r < 32; ++r) {
        unsigned* p = cnt + (size_t)(w * 32 + r) * NBUCK + b;
        const unsigned v = *p;
        *p = sum;
        sum += v;
    }
    wgsum[w * NBUCK + b] = sum;
}

// ---------------- K3: bucket bases + chunk offsets ---------------------------
__global__ __launch_bounds__(1024) void hsnt_scan_b(
    unsigned* __restrict__ wgsum, unsigned* __restrict__ wgoff)
{
    __shared__ unsigned s[NBUCK];
    const int b = threadIdx.x;

    unsigned tot = 0u;
#pragma unroll 4
    for (int w = 0; w < NW; ++w) tot += wgsum[w * NBUCK + b];

    s[b] = tot;
    __syncthreads();
    unsigned acc = tot;
    for (int off = 1; off < NBUCK; off <<= 1) {
        const unsigned add = (b >= off) ? s[b - off] : 0u;
        __syncthreads();
        acc += add;
        s[b] = acc;
        __syncthreads();
    }
    unsigned run = acc - tot;

#pragma unroll 4
    for (int w = 0; w < NW; ++w) {
        const unsigned v = wgsum[w * NBUCK + b];
        wgoff[w * NBUCK + b] = run;
        run += v;
    }
}

// ---------------- K4: scatter (LDS ranks, float4 loads) ----------------------
__global__ __launch_bounds__(256) void hsnt_scatter2(
    const float* __restrict__ uv,
    const unsigned* __restrict__ cnt,
    const unsigned* __restrict__ wgoff,
    float2* __restrict__ uvs, unsigned* __restrict__ inv)
{
    __shared__ unsigned lh[NBUCK];
    __shared__ unsigned lbase[NBUCK];
    const int blk = blockIdx.x;

    for (int i = threadIdx.x; i < NBUCK; i += 256) lh[i] = 0u;
    __syncthreads();

    const int i4 = blk * 1024 + threadIdx.x * 4;
    const float4 gx4 = *(const float4*)&uv[i4];
    const float4 gy4 = *(const float4*)&uv[NPIX + i4];
    const float gx[4] = { gx4.x, gx4.y, gx4.z, gx4.w };
    const float gy[4] = { gy4.x, gy4.y, gy4.z, gy4.w };

    int bk[4];
    unsigned rk[4];
#pragma unroll
    for (int k = 0; k < 4; ++k) {
        bk[k] = bucket_of(gx[k], gy[k]);
        rk[k] = atomicAdd(&lh[bk[k]], 1u);
    }

    const unsigned* crow = cnt + (size_t)blk * NBUCK;
    const unsigned* wrow = wgoff + (size_t)(blk >> 5) * NBUCK;
    for (int i = threadIdx.x; i < NBUCK; i += 256)
        lbase[i] = crow[i] + wrow[i];
    __syncthreads();

    unsigned pos[4];
#pragma unroll
    for (int k = 0; k < 4; ++k) {
        pos[k] = lbase[bk[k]] + rk[k];
        uvs[pos[k]] = make_float2(gx[k], gy[k]);
    }
    *(uint4*)&inv[i4] = make_uint4(pos[0], pos[1], pos[2], pos[3]);
}

// ---------------- K5: bucketed sampling --------------------------------------
__device__ __forceinline__ void accum_texel(
    float* __restrict__ acc, const __half* __restrict__ tp, const float w)
{
    union U { uint4 u; __half2 h[4]; } a, b;
    a.u = *(const uint4*)tp;
    b.u = *(const uint4*)(tp + 8);
#pragma unroll
    for (int i = 0; i < 4; ++i) {
        const float2 f = __half22float2(a.h[i]);
        acc[2 * i]     = fmaf(f.x, w, acc[2 * i]);
        acc[2 * i + 1] = fmaf(f.y, w, acc[2 * i + 1]);
        const float2 g = __half22float2(b.h[i]);
        acc[8 + 2 * i]     = fmaf(g.x, w, acc[8 + 2 * i]);
        acc[8 + 2 * i + 1] = fmaf(g.y, w, acc[8 + 2 * i + 1]);
    }
}

__global__ __launch_bounds__(256) void hsnt_sample_b(
    const float2* __restrict__ uvs,
    const __half* __restrict__ tex,
    __half* __restrict__ tmp)
{
    // XCD-chunked swizzle: each XCD walks a contiguous range of sorted order
    const int bid = blockIdx.x;
    const int swz = (bid & 7) * (4096 / 8) + (bid >> 3);
    const int s = swz * 256 + threadIdx.x;

    const float2 g = uvs[s];
    const float gx = g.x;
    const float gy = g.y;

    float acc[NCH];
#pragma unroll
    for (int c = 0; c < NCH; ++c) acc[c] = 0.0f;

    const int BASE[4] = { L0_BASE, L1_BASE, L2_BASE, L3_BASE };

#pragma unroll
    for (int l = 0; l < 4; ++l) {
        const int   W  = 1024 >> l;
        const float Wf = (float)W;

        float x = fminf(fmaxf(fmaf(gx + 1.0f, Wf * 0.5f, -0.5f), 0.0f), Wf - 1.0f);
        float y = fminf(fmaxf(fmaf(gy + 1.0f, Wf * 0.5f, -0.5f), 0.0f), Wf - 1.0f);

        const float x0f = floorf(x);
        const float y0f = floorf(y);
        const float wx = x - x0f;
        const float wy = y - y0f;
        const int x0 = (int)x0f;
        const int y0 = (int)y0f;
        const int x1 = min(x0 + 1, W - 1);
        const int y1 = min(y0 + 1, W - 1);

        const float w11 = wx * wy;
        const float w10 = wy - w11;
        const float w01 = wx - w11;
        const float w00 = 1.0f - wx - wy + w11;

        const int r0 = BASE[l] + y0 * W;
        const int r1 = BASE[l] + y1 * W;

        accum_texel(acc, tex + ((size_t)(r0 + x0) << 4), w00);
        accum_texel(acc, tex + ((size_t)(r0 + x1) << 4), w01);
        accum_texel(acc, tex + ((size_t)(r1 + x0) << 4), w10);
        accum_texel(acc, tex + ((size_t)(r1 + x1) << 4), w11);
    }

    __half h[NCH];
#pragma unroll
    for (int c = 0; c < NCH; ++c) h[c] = __float2half(acc[c]);

    uint4* dst = (uint4*)(tmp + ((size_t)s << 4));
    dst[0] = *(const uint4*)&h[0];
    dst[1] = *(const uint4*)&h[8];
}

// ---------------- K6: unpermute, 4 px / thread -------------------------------
__global__ __launch_bounds__(256) void hsnt_unperm(
    const unsigned* __restrict__ inv,
    const __half* __restrict__ tmp,
    float* __restrict__ out)
{
    const int i4 = (blockIdx.x * 256 + threadIdx.x) * 4;
    const uint4 r4 = *(const uint4*)&inv[i4];

    union T { uint4 u[2]; __half h[16]; } t[4];
    const unsigned r[4] = { r4.x, r4.y, r4.z, r4.w };
#pragma unroll
    for (int p = 0; p < 4; ++p) {
        const uint4* q = (const uint4*)(tmp + ((size_t)r[p] << 4));
        t[p].u[0] = q[0];
        t[p].u[1] = q[1];
    }

#pragma unroll
    for (int c = 0; c < NCH; ++c) {
        const float4 v = make_float4(__half2float(t[0].h[c]),
                                     __half2float(t[1].h[c]),
                                     __half2float(t[2].h[c]),
                                     __half2float(t[3].h[c]));
        *(float4*)&out[(size_t)c * NPIX + i4] = v;
    }
}

// ---------------- direct fp16 path (fallback) --------------------------------
__global__ __launch_bounds__(256) void hsnt_transpose_h(
    const float* __restrict__ data, __half* __restrict__ tex)
{
    int b = blockIdx.x;
    int base, offY, logW;
    if (b < 4096)      { base = L0_BASE; offY = 0;    logW = 10; }
    else if (b < 5120) { base = L1_BASE; offY = 1024; logW = 9;  b -= 4096; }
    else if (b < 5376) { base = L2_BASE; offY = 1536; logW = 8;  b -= 5120; }
    else               { base = L3_BASE; offY = 1792; logW = 7;  b -= 5376; }

    const int t = b * 256 + threadIdx.x;
    const int y = t >> logW;
    const int x = t & ((1 << logW) - 1);

    const float* src = data + (size_t)(offY + y) * DATA_ROWSTRIDE + x;
    __half h[NCH];
#pragma unroll
    for (int c = 0; c < NCH; ++c)
        h[c] = __float2half(src[(size_t)c * DATA_CHSTRIDE]);

    uint4* dst = (uint4*)(tex + ((size_t)(base + t) << 4));
    dst[0] = *(const uint4*)&h[0];
    dst[1] = *(const uint4*)&h[8];
}

__global__ __launch_bounds__(256) void hsnt_sample_h(
    const float* __restrict__ uv,
    const __half* __restrict__ tex,
    float* __restrict__ out)
{
    const int idx = blockIdx.x * blockDim.x + threadIdx.x;
    if (idx >= NPIX) return;

    const float gx = uv[idx];
    const float gy = uv[NPIX + idx];

    float acc[NCH];
#pragma unroll
    for (int c = 0; c < NCH; ++c) acc[c] = 0.0f;

    const int BASE[4] = { L0_BASE, L1_BASE, L2_BASE, L3_BASE };

#pragma unroll
    for (int l = 0; l < 4; ++l) {
        const int   W  = 1024 >> l;
        const float Wf = (float)W;
        float x = fminf(fmaxf(fmaf(gx + 1.0f, Wf * 0.5f, -0.5f), 0.0f), Wf - 1.0f);
        float y = fminf(fmaxf(fmaf(gy + 1.0f, Wf * 0.5f, -0.5f), 0.0f), Wf - 1.0f);
        const float x0f = floorf(x);
        const float y0f = floorf(y);
        const float wx = x - x0f;
        const float wy = y - y0f;
        const int x0 = (int)x0f;
        const int y0 = (int)y0f;
        const int x1 = min(x0 + 1, W - 1);
        const int y1 = min(y0 + 1, W - 1);
        const float w11 = wx * wy;
        const float w10 = wy - w11;
        const float w01 = wx - w11;
        const float w00 = 1.0f - wx - wy + w11;
        const int r0 = BASE[l] + y0 * W;
        const int r1 = BASE[l] + y1 * W;
        accum_texel(acc, tex + ((size_t)(r0 + x0) << 4), w00);
        accum_texel(acc, tex + ((size_t)(r0 + x1) << 4), w01);
        accum_texel(acc, tex + ((size_t)(r1 + x0) << 4), w10);
        accum_texel(acc, tex + ((size_t)(r1 + x1) << 4), w11);
    }

#pragma unroll
    for (int c = 0; c < NCH; ++c)
        out[(size_t)c * NPIX + idx] = acc[c];
}

// ---------------- naive fallback ---------------------------------------------
__global__ __launch_bounds__(256) void hsnt_naive(
    const float* __restrict__ uv,
    const float* __restrict__ data,
    float* __restrict__ out)
{
    const int idx = blockIdx.x * blockDim.x + threadIdx.x;
    if (idx >= NPIX) return;

    const float gx = uv[idx];
    const float gy = uv[NPIX + idx];

    float acc[NCH];
#pragma unroll
    for (int c = 0; c < NCH; ++c) acc[c] = 0.0f;

    int offY = 0;
    int W = 1024;
#pragma unroll
    for (int l = 0; l < 4; ++l) {
        const float Wf = (float)W;
        float x = fminf(fmaxf(fmaf(gx + 1.0f, Wf * 0.5f, -0.5f), 0.0f), Wf - 1.0f);
        float y = fminf(fmaxf(fmaf(gy + 1.0f, Wf * 0.5f, -0.5f), 0.0f), Wf - 1.0f);
        const float x0f = floorf(x);
        const float y0f = floorf(y);
        const float wx = x - x0f;
        const float wy = y - y0f;
        const int x0 = (int)x0f;
        const int y0 = (int)y0f;
        const int x1 = min(x0 + 1, W - 1);
        const int y1 = min(y0 + 1, W - 1);
        const float w11 = wx * wy;
        const float w10 = wy - w11;
        const float w01 = wx - w11;
        const float w00 = 1.0f - wx - wy + w11;
        const int r0 = offY + y0;
        const int r1 = offY + y1;
        const float* p00 = data + (size_t)r0 * DATA_ROWSTRIDE + x0;
        const float* p01 = data + (size_t)r0 * DATA_ROWSTRIDE + x1;
        const float* p10 = data + (size_t)r1 * DATA_ROWSTRIDE + x0;
        const float* p11 = data + (size_t)r1 * DATA_ROWSTRIDE + x1;
#pragma unroll
        for (int c = 0; c < NCH; ++c) {
            const size_t co = (size_t)c * DATA_CHSTRIDE;
            acc[c] = fmaf(p00[co], w00,
                     fmaf(p01[co], w01,
                     fmaf(p10[co], w10,
                     fmaf(p11[co], w11, acc[c]))));
        }
        offY += W;
        W >>= 1;
    }
#pragma unroll
    for (int c = 0; c < NCH; ++c)
        out[(size_t)c * NPIX + idx] = acc[c];
}

extern "C" void kernel_launch(void* const* d_in, const int* in_sizes, int n_in,
                              void* d_out, int out_size, void* d_ws, size_t ws_size,
                              hipStream_t stream) {
    const float* uv   = (const float*)d_in[0];   // [1,2,1024,1024]
    const float* data = (const float*)d_in[1];   // [1,16,2048,1024]
    float* out = (float*)d_out;                  // [1,16,1024,1024]

    const int grid = NPIX / 256;                 // 4096

    if (ws_size >= WS_FULL && d_ws != nullptr) {
        char* ws = (char*)d_ws;
        __half*   tex   = (__half*)ws;
        float2*   uvs   = (float2*)(ws + UVS_OFF);
        unsigned* inv   = (unsigned*)(ws + INV_OFF);
        __half*   tmp   = (__half*)(ws + TMP_OFF);
        unsigned* cnt   = (unsigned*)(ws + CNT_OFF);   // aliases tmp head
        unsigned* wgsum = (unsigned*)(ws + WGS_OFF);
        unsigned* wgoff = (unsigned*)(ws + WGO_OFF);

        hsnt_prep<<<NBLK + TRANS_BLKS, 256, 0, stream>>>(data, uv, tex, cnt);
        hsnt_scan_a<<<NW, 1024, 0, stream>>>(cnt, wgsum);
        hsnt_scan_b<<<1, 1024, 0, stream>>>(wgsum, wgoff);
        hsnt_scatter2<<<NBLK, 256, 0, stream>>>(uv, cnt, wgoff, uvs, inv);
        hsnt_sample_b<<<grid, 256, 0, stream>>>(uvs, tex, tmp);
        hsnt_unperm<<<NPIX / 1024, 256, 0, stream>>>(inv, tmp, out);
    } else if (ws_size >= WS_DIRECT && d_ws != nullptr) {
        __half* tex = (__half*)d_ws;
        hsnt_transpose_h<<<TRANS_BLKS, 256, 0, stream>>>(data, tex);
        hsnt_sample_h<<<grid, 256, 0, stream>>>(uv, tex, out);
    } else {
        hsnt_naive<<<grid, 256, 0, stream>>>(uv, data, out);
    }
}